// Round 10
// baseline (172.968 us; speedup 1.0000x reference)
//
#include <hip/hip_runtime.h>

// NonLocalBlock (SAGAN non-local) fused pipeline for MI355X / gfx950.
// B=8, Cin=256, H=W=64 (HW=4096), Cout=512. Workspace (~46 MB of d_ws):
//   [0,16MB)   xT   fp16 [8][4096][256]
//   [16,20MB)  Q    fp16 [8][4096][64]
//   [20,21MB)  Kp   fp16 [8][1024][64]   (8B-half-swapped per key-row bit3)
//   [21,25MB)  V    fp16 [8][256][1024]  (8B-half-swapped per ch-row bit3)
//   [25MB+0)   Wproj fp16 [384][256]; [25MB+512K) Wcat fp16 [512][512]
//   [26,46MB)  F    fp16 [8][320][4096]; att aliases F
//
// R9->R10: flash was VALU-bound (53% busy) with 4x-duplicated QK^T+softmax
// across the 4 channel-group waves (MfmaUtil 20% = exactly the duplicated
// FLOPs at peak). Key-split specialization: 8 waves = 2 rg x 2 p(key-half)
// x 2 q(ch-half). Each wave: S for its 32 keys only (4 MFMA, 16 exp2) and
// PV for 128 ch over those keys (8 MFMA, o=64 AGPRs). Independent (m,l,o)
// per wave; exact split-softmax merge across p-pairs at the end via LDS
// (reuses K/V buffers). Per-block: MFMA/kt 128->96, exp2/kt 256->128.

typedef _Float16 f16;
typedef f16 f16x4 __attribute__((ext_vector_type(4)));
typedef f16 f16x8 __attribute__((ext_vector_type(8)));
typedef f16 h2 __attribute__((ext_vector_type(2)));
typedef float f32x4 __attribute__((ext_vector_type(4)));
typedef float f32x16 __attribute__((ext_vector_type(16)));
typedef int int2v __attribute__((ext_vector_type(2)));

#define MFMA16(a, b, c) __builtin_amdgcn_mfma_f32_16x16x32_f16((a), (b), (c), 0, 0, 0)
#define MFMA32(a, b, c) __builtin_amdgcn_mfma_f32_32x32x16_f16((a), (b), (c), 0, 0, 0)

__device__ __forceinline__ void gload16(const void* src, void* dst_lds) {
  __builtin_amdgcn_global_load_lds(
      (const __attribute__((address_space(1))) void*)src,
      (__attribute__((address_space(3))) void*)dst_lds, 16, 0, 0);
}

__device__ __forceinline__ f16x8 cat8(f16x4 a, f16x4 b) {
  f16x8 r;
  r[0] = a[0]; r[1] = a[1]; r[2] = a[2]; r[3] = a[3];
  r[4] = b[0]; r[5] = b[1]; r[6] = b[2]; r[7] = b[3];
  return r;
}

__device__ __forceinline__ h2 pk2(float a, float b) {
  return __builtin_bit_cast(h2, __builtin_amdgcn_cvt_pkrtz(a, b));
}

__device__ __forceinline__ float asf(int x) { return __builtin_bit_cast(float, x); }
__device__ __forceinline__ int asi(float x) { return __builtin_bit_cast(int, x); }

// -------------------------------------------------------------------------
__global__ __launch_bounds__(256, 4)
void k_prep_w(const float* __restrict__ wt, const float* __restrict__ wp,
              const float* __restrict__ wg, const float* __restrict__ wo,
              const float* __restrict__ wr, const float* __restrict__ gamma,
              f16* __restrict__ Wproj, f16* __restrict__ Wcat) {
  int i = blockIdx.x * 256 + threadIdx.x;
  const float s = 0.08838834764831845f;    // sqrt(2/256)
  const float is2 = 0.7071067811865476f;   // 1/sqrt(2)
  if (i < 384 * 256) {
    float v = (i < 64 * 256) ? wt[i]
              : (i < 128 * 256 ? wp[i - 64 * 256] : wg[i - 128 * 256]);
    Wproj[i] = (f16)(v * s);
  } else {
    int j = i - 384 * 256;
    if (j < 512 * 512) {
      int r = j >> 9, c = j & 511;
      float v = (c < 256) ? wo[r * 256 + c] * (gamma[0] * s * is2)
                          : wr[r * 256 + (c - 256)] * (s * is2);
      Wcat[j] = (f16)v;
    }
  }
}

// -------------------------------------------------------------------------
// Transpose x [b][256][4096] fp32 -> xT [b][4096][256] fp16 via 64x64 LDS tiles.
__global__ __launch_bounds__(256, 4)
void k_transpose(const float* __restrict__ x, f16* __restrict__ xT) {
  __shared__ f16 tile[64 * 72];
  int b = blockIdx.z, nt = blockIdx.y, ct = blockIdx.x;
  int t = threadIdx.x;
  {
    int c = t >> 2, nch = (t & 3) * 16;
    const float* src = x + (((size_t)b * 256 + ct * 64 + c) << 12) + nt * 64 + nch;
    float4 v0 = *(const float4*)(src);
    float4 v1 = *(const float4*)(src + 4);
    float4 v2 = *(const float4*)(src + 8);
    float4 v3 = *(const float4*)(src + 12);
    f16x8 a = {(f16)v0.x, (f16)v0.y, (f16)v0.z, (f16)v0.w,
               (f16)v1.x, (f16)v1.y, (f16)v1.z, (f16)v1.w};
    f16x8 bb = {(f16)v2.x, (f16)v2.y, (f16)v2.z, (f16)v2.w,
                (f16)v3.x, (f16)v3.y, (f16)v3.z, (f16)v3.w};
    *(f16x8*)&tile[c * 72 + nch] = a;
    *(f16x8*)&tile[c * 72 + nch + 8] = bb;
  }
  __syncthreads();
  {
    int n = t >> 2, cch = (t & 3) * 16;
    f16 tmp[16];
#pragma unroll
    for (int i = 0; i < 16; i++) tmp[i] = tile[(cch + i) * 72 + n];
    f16x8 a, bb;
#pragma unroll
    for (int i = 0; i < 8; i++) { a[i] = tmp[i]; bb[i] = tmp[8 + i]; }
    f16* dst = xT + (((size_t)b * 4096 + nt * 64 + n) << 8) + ct * 64 + cch;
    *(f16x8*)dst = a;
    *(f16x8*)(dst + 8) = bb;
  }
}

// -------------------------------------------------------------------------
// Merged projection GEMM: out rows = Wproj rows [mt*64, mt*64+64).
// mt==0 -> theta -> Q[b][n][64]; mt>=1 -> phi|g -> F[b][jj][n].
__global__ __launch_bounds__(256, 2)
void k_gemm_projq(const f16* __restrict__ xT, const f16* __restrict__ Wproj,
                  f16* __restrict__ Q, f16* __restrict__ F) {
  __shared__ f16 Alds[64 * 64];
  __shared__ f16 Blds[128 * 64];
  int b = blockIdx.z, mt = blockIdx.x, nt = blockIdx.y;
  int lane = threadIdx.x & 63, wave = threadIdx.x >> 6;
  int wm = wave >> 1, wn = wave & 1;
  f32x4 acc[2][4];
#pragma unroll
  for (int mf = 0; mf < 2; mf++)
#pragma unroll
    for (int nf = 0; nf < 4; nf++) acc[mf][nf] = (f32x4){0, 0, 0, 0};
  const f16* Abase = Wproj + ((mt * 64) << 8);
  const f16* Bbase = xT + (((size_t)b * 4096 + nt * 128) << 8);
  for (int k0 = 0; k0 < 256; k0 += 64) {
    __syncthreads();
#pragma unroll
    for (int i = 0; i < 2; i++) {
      int chunk = i * 256 + threadIdx.x;
      int row = chunk >> 3, cc = chunk & 7, scc = cc ^ (row & 7);
      gload16(Abase + (row << 8) + k0 + scc * 8, (char*)Alds + (i * 256 + wave * 64) * 16);
    }
#pragma unroll
    for (int i = 0; i < 4; i++) {
      int chunk = i * 256 + threadIdx.x;
      int row = chunk >> 3, cc = chunk & 7, scc = cc ^ (row & 7);
      gload16(Bbase + (row << 8) + k0 + scc * 8, (char*)Blds + (i * 256 + wave * 64) * 16);
    }
    __syncthreads();
#pragma unroll
    for (int ks = 0; ks < 2; ks++) {
      int cb = ((lane >> 4) * 8 + ks * 32) * 2;
      f16x8 af[2], bf[4];
#pragma unroll
      for (int mf = 0; mf < 2; mf++) {
        int row = wm * 32 + mf * 16 + (lane & 15);
        af[mf] = *(const f16x8*)((const char*)Alds + row * 128 + (cb ^ ((row & 7) << 4)));
      }
#pragma unroll
      for (int nf = 0; nf < 4; nf++) {
        int row = wn * 64 + nf * 16 + (lane & 15);
        bf[nf] = *(const f16x8*)((const char*)Blds + row * 128 + (cb ^ ((row & 7) << 4)));
      }
#pragma unroll
      for (int mf = 0; mf < 2; mf++)
#pragma unroll
        for (int nf = 0; nf < 4; nf++) acc[mf][nf] = MFMA16(af[mf], bf[nf], acc[mf][nf]);
    }
  }
#pragma unroll
  for (int mf = 0; mf < 2; mf++)
#pragma unroll
    for (int nf = 0; nf < 4; nf++)
#pragma unroll
      for (int r = 0; r < 4; r++) {
        int jl = wm * 32 + mf * 16 + (lane >> 4) * 4 + r;  // 0..63
        int n = nt * 128 + wn * 64 + nf * 16 + (lane & 15);
        f16 v = (f16)acc[mf][nf][r];
        if (mt == 0)
          Q[(((size_t)b * 4096 + n) << 6) + jl] = v;
        else
          F[(((size_t)b * 320 + (mt - 1) * 64 + jl) << 12) + n] = v;
      }
}

// -------------------------------------------------------------------------
// 2x2 maxpool: F[b][jj][4096] -> jj<64: Kp[b][m][jj] (phi), jj>=64: V[b][jj-64][m].
// Kp/V written with the 8B-half swap (row-bit3) for conflict-free flash reads.
__global__ __launch_bounds__(256, 4)
void k_pool(const f16* __restrict__ F, f16* __restrict__ Kp, f16* __restrict__ V) {
  int id = blockIdx.x * 256 + threadIdx.x;  // < 8*320*32 = 81920
  int ph = id & 31;
  int rest = id >> 5;
  int jj = rest % 320;
  int b = rest / 320;
  const f16x8* r0 = (const f16x8*)(F + (((size_t)b * 320 + jj) << 12) + ph * 128);
  const f16x8* r1 = r0 + 8;
  f16 outv[32];
#pragma unroll
  for (int ch = 0; ch < 8; ch++) {
    f16x8 u = r0[ch], v = r1[ch];
#pragma unroll
    for (int p = 0; p < 4; p++) {
      float m1 = fmaxf(fmaxf((float)u[2 * p], (float)u[2 * p + 1]),
                       fmaxf((float)v[2 * p], (float)v[2 * p + 1]));
      outv[ch * 4 + p] = (f16)m1;
    }
  }
  int m0 = ph * 32;
  if (jj < 64) {
#pragma unroll
    for (int p = 0; p < 32; p++) {
      int m = m0 + p;
      int jx = jj ^ ((((m) >> 3) & 1) << 2);
      Kp[((size_t)b * 1024 + m) * 64 + jx] = outv[p];
    }
  } else {
    int c = jj - 64;
    int flip = ((c >> 3) & 1) << 2;
    f16* dst = V + (((size_t)b * 256 + c) << 10) + m0;
#pragma unroll
    for (int c8 = 0; c8 < 4; c8++) {
      f16x8 w;
#pragma unroll
      for (int i = 0; i < 8; i++) w[i] = outv[c8 * 8 + (i ^ flip)];
      *(f16x8*)(dst + c8 * 8) = w;
    }
  }
}

// -------------------------------------------------------------------------
// Flash attention (32x32 swapped QK^T, key-split): Q [4096][64], K [1024][64],
// V [256][1024] -> att [n][c]. 512 thr = 8 waves = 2 rg(32q) x 2 p(key-half)
// x 2 q(128ch). Each wave: S for its 32 keys (4 MFMA, 16 exp2), PV for 128 ch
// (8 MFMA, o=4xf32x16 AGPR). Exact split-softmax merge across p at the end.
__global__ __launch_bounds__(512, 4)
void k_flash(const f16* __restrict__ Q, const f16* __restrict__ Kp,
             const f16* __restrict__ V, f16* __restrict__ att) {
  __shared__ f16 Klds[2][64 * 64];    // [key][ch], 8KB each
  __shared__ f16 Vlds[2][256 * 64];   // [ch][key], 32KB each
  int b = blockIdx.y, qt = blockIdx.x;
  int tid = threadIdx.x;
  int lane = tid & 63, wave = tid >> 6;
  int rg = wave >> 2;          // q-row group (32 rows)
  int p = (wave >> 1) & 1;     // key half: keys 32p..32p+31 of each tile
  int qh = wave & 1;           // channel half: 128 ch at qh*128
  int l31 = lane & 31, h5 = lane >> 5;
  const f16* Kb = Kp + ((size_t)b << 16);
  const f16* Vb = V + ((size_t)b << 18);
  const float L2E = 1.44269504f;

  const f16* Qrow = Q + (((size_t)b * 4096 + qt * 64 + rg * 32 + l31) << 6);
  f16x8 qf[4];
#pragma unroll
  for (int t = 0; t < 4; t++) {
    f16x4 lo = *(const f16x4*)(Qrow + t * 16 + 4 * h5);
    f16x4 hi = *(const f16x4*)(Qrow + t * 16 + 8 + 4 * h5);
    qf[t] = cat8(lo, hi);
  }
  f32x16 oT[4];
#pragma unroll
  for (int u = 0; u < 4; u++)
#pragma unroll
    for (int i = 0; i < 16; i++) oT[u][i] = 0.f;
  float m = -1e30f, lsum = 0.f;

#define STAGE(bufi, kt)                                                          \
  {                                                                              \
    {                                                                            \
      int chunk = tid;                                                           \
      int row = chunk >> 3, cc = chunk & 7, scc = cc ^ (row & 7);                \
      gload16(Kb + (((kt) * 64 + row) << 6) + scc * 8,                           \
              (char*)&Klds[bufi][0] + chunk * 16);                               \
    }                                                                            \
    _Pragma("unroll") for (int i = 0; i < 4; i++) {                              \
      int chunk = i * 512 + tid;                                                 \
      int row = chunk >> 3, cc = chunk & 7, scc = cc ^ (row & 7);                \
      gload16(Vb + ((size_t)row << 10) + (kt) * 64 + scc * 8,                    \
              (char*)&Vlds[bufi][0] + chunk * 16);                               \
    }                                                                            \
  }

  STAGE(0, 0);
  __syncthreads();
  int buf = 0;
  const int swx = ((l31 & 7) << 4) | (((l31 >> 3) & 1) << 3);
  const int krow = l31 + 32 * p;  // this wave's K rows (same swx: bits 0..3 equal)
  for (int kt = 0; kt < 16; ++kt) {
    if (kt < 15) STAGE(buf ^ 1, kt + 1);
    // ---- S^T = K Q^T for this wave's 32 keys
    f32x16 S;
#pragma unroll
    for (int i = 0; i < 16; i++) S[i] = 0.f;
    const char* Kbase = (const char*)&Klds[buf][0];
#pragma unroll
    for (int t = 0; t < 4; t++) {
      int ob = t * 32 + 8 * h5;
      f16x4 a0 = *(const f16x4*)(Kbase + krow * 128 + (ob ^ swx));
      f16x4 a1 = *(const f16x4*)(Kbase + krow * 128 + ((ob + 16) ^ swx));
      S = MFMA32(cat8(a0, a1), qf[t], S);
    }
    // ---- lane-local max over this wave's 32 keys (other interleave in lane^32)
    float mx = S[0];
#pragma unroll
    for (int i = 1; i < 16; i++) mx = fmaxf(mx, S[i]);
    int2v pr = __builtin_amdgcn_permlane32_swap(asi(mx), asi(mx), false, false);
    mx = fmaxf(asf(pr[0]), asf(pr[1]));
    if (__any(mx > m + 8.f)) {
      float mnew = fmaxf(m, mx);
      float corr = __builtin_amdgcn_exp2f((m - mnew) * L2E);
      m = mnew;
      lsum *= corr;
#pragma unroll
      for (int reg = 0; reg < 16; reg++) {
        float cr = __shfl(corr, (reg & 3) + 8 * (reg >> 2) + 4 * h5, 64);
#pragma unroll
        for (int u = 0; u < 4; u++) oT[u][reg] *= cr;
      }
    }
    // ---- exp -> pack -> PV over this wave's 128 channels
    const char* Vbase = (const char*)&Vlds[buf][0];
    float lp = 0.f;
#pragma unroll
    for (int tp = 0; tp < 2; tp++) {
      float ee[8];
#pragma unroll
      for (int j = 0; j < 8; j++) {
        ee[j] = __builtin_amdgcn_exp2f((S[tp * 8 + j] - m) * L2E);
        lp += ee[j];
      }
      h2 p0 = pk2(ee[0], ee[1]);
      h2 p1 = pk2(ee[2], ee[3]);
      h2 p2 = pk2(ee[4], ee[5]);
      h2 p3 = pk2(ee[6], ee[7]);
      f16x8 af = {p0[0], p0[1], p1[0], p1[1], p2[0], p2[1], p3[0], p3[1]};
      int ob = (2 * p + tp) * 32 + 8 * h5;
      __builtin_amdgcn_s_setprio(1);
#pragma unroll
      for (int u = 0; u < 4; u++) {
        int row = qh * 128 + u * 32 + l31;
        f16x4 va = *(const f16x4*)(Vbase + row * 128 + (ob ^ swx));
        f16x4 vb = *(const f16x4*)(Vbase + row * 128 + ((ob + 16) ^ swx));
        oT[u] = MFMA32(af, cat8(va, vb), oT[u]);
      }
      __builtin_amdgcn_s_setprio(0);
    }
    lsum += lp;
    __syncthreads();
    buf ^= 1;
  }
#undef STAGE
  // ---- merge across h5 pair (this wave's 32 keys)
  int2v pl = __builtin_amdgcn_permlane32_swap(asi(lsum), asi(lsum), false, false);
  float lhalf = asf(pl[0]) + asf(pl[1]);
  // ---- split-softmax merge across p-pairs via LDS (K/V buffers reused)
  float* mergeO = (float*)&Vlds[0][0];   // 4 slots x 16KB
  float* mergeML = (float*)&Klds[0][0];  // 4 slots x 512B
  int slot = rg * 2 + qh;
  __syncthreads();
  if (p == 1) {
    mergeML[slot * 128 + lane] = m;
    mergeML[slot * 128 + 64 + lane] = lhalf;
#pragma unroll
    for (int u = 0; u < 4; u++)
#pragma unroll
      for (int i = 0; i < 16; i++)
        mergeO[slot * 4096 + (u * 16 + i) * 64 + lane] = oT[u][i];
  }
  __syncthreads();
  if (p == 0) {
    float m1 = mergeML[slot * 128 + lane];
    float l1 = mergeML[slot * 128 + 64 + lane];
    float mst = fmaxf(m, m1);
    float a0 = __builtin_amdgcn_exp2f((m - mst) * L2E);
    float a1 = __builtin_amdgcn_exp2f((m1 - mst) * L2E);
    float inv = 1.f / (lhalf * a0 + l1 * a1);
    int nbase = qt * 64 + rg * 32;
#pragma unroll
    for (int reg = 0; reg < 16; reg++) {
      int qr = (reg & 3) + 8 * (reg >> 2) + 4 * h5;
      float A0 = __shfl(a0, qr, 64);
      float A1 = __shfl(a1, qr, 64);
      float IV = __shfl(inv, qr, 64);
      f16* dst = att + (((size_t)b * 4096 + nbase + qr) << 8) + qh * 128 + l31;
#pragma unroll
      for (int u = 0; u < 4; u++) {
        float o1v = mergeO[slot * 4096 + (u * 16 + reg) * 64 + lane];
        dst[u * 32] = (f16)((oT[u][reg] * A0 + o1v * A1) * IV);
      }
    }
  }
}

// -------------------------------------------------------------------------
// Output GEMM: out[b][o][n] = sum_{k<512} Wcat[o][k] * Bcat[n][k], Bcat=[att|xT].
__global__ __launch_bounds__(256, 2)
void k_gemm_out(const f16* __restrict__ Wcat, const f16* __restrict__ att,
                const f16* __restrict__ xT, float* __restrict__ out) {
  __shared__ f16 Alds[128 * 64];
  __shared__ f16 Blds[128 * 64];
  int b = blockIdx.z, mt = blockIdx.x, nt = blockIdx.y;
  int lane = threadIdx.x & 63, wave = threadIdx.x >> 6;
  int wm = wave >> 1, wn = wave & 1;
  f32x4 acc[4][4];
#pragma unroll
  for (int mf = 0; mf < 4; mf++)
#pragma unroll
    for (int nf = 0; nf < 4; nf++) acc[mf][nf] = (f32x4){0, 0, 0, 0};
  const f16* Abase = Wcat + (size_t)(mt * 128) * 512;
  for (int k0 = 0; k0 < 512; k0 += 64) {
    __syncthreads();
#pragma unroll
    for (int i = 0; i < 4; i++) {
      int chunk = i * 256 + threadIdx.x;
      int row = chunk >> 3, cc = chunk & 7, scc = cc ^ (row & 7);
      gload16(Abase + row * 512 + k0 + scc * 8, (char*)Alds + (i * 256 + wave * 64) * 16);
    }
    const f16* Bcol = (k0 < 256) ? (att + (((size_t)b * 4096 + nt * 128) << 8))
                                 : (xT + (((size_t)b * 4096 + nt * 128) << 8));
    int kk = (k0 < 256) ? k0 : (k0 - 256);
#pragma unroll
    for (int i = 0; i < 4; i++) {
      int chunk = i * 256 + threadIdx.x;
      int row = chunk >> 3, cc = chunk & 7, scc = cc ^ (row & 7);
      gload16(Bcol + (row << 8) + kk + scc * 8, (char*)Blds + (i * 256 + wave * 64) * 16);
    }
    __syncthreads();
#pragma unroll
    for (int ks = 0; ks < 2; ks++) {
      int cb = ((lane >> 4) * 8 + ks * 32) * 2;
      f16x8 af[4], bf[4];
#pragma unroll
      for (int mf = 0; mf < 4; mf++) {
        int row = wm * 64 + mf * 16 + (lane & 15);
        af[mf] = *(const f16x8*)((const char*)Alds + row * 128 + (cb ^ ((row & 7) << 4)));
      }
#pragma unroll
      for (int nf = 0; nf < 4; nf++) {
        int row = wn * 64 + nf * 16 + (lane & 15);
        bf[nf] = *(const f16x8*)((const char*)Blds + row * 128 + (cb ^ ((row & 7) << 4)));
      }
#pragma unroll
      for (int mf = 0; mf < 4; mf++)
#pragma unroll
        for (int nf = 0; nf < 4; nf++) acc[mf][nf] = MFMA16(af[mf], bf[nf], acc[mf][nf]);
    }
  }
#pragma unroll
  for (int mf = 0; mf < 4; mf++)
#pragma unroll
    for (int nf = 0; nf < 4; nf++)
#pragma unroll
      for (int r = 0; r < 4; r++) {
        int oo = mt * 128 + wm * 64 + mf * 16 + (lane >> 4) * 4 + r;
        int n = nt * 128 + wn * 64 + nf * 16 + (lane & 15);
        out[(((size_t)b * 512 + oo) << 12) + n] = acc[mf][nf][r];
      }
}

// -------------------------------------------------------------------------
extern "C" void kernel_launch(void* const* d_in, const int* in_sizes, int n_in,
                              void* d_out, int out_size, void* d_ws, size_t ws_size,
                              hipStream_t stream) {
  const float* x = (const float*)d_in[0];
  const float* wt = (const float*)d_in[1];
  const float* wp = (const float*)d_in[2];
  const float* wg = (const float*)d_in[3];
  const float* wo = (const float*)d_in[4];
  const float* wr = (const float*)d_in[5];
  const float* gm = (const float*)d_in[6];
  float* out = (float*)d_out;
  char* ws = (char*)d_ws;
  const size_t MB = 1024 * 1024;
  f16* xT = (f16*)(ws);
  f16* Qb = (f16*)(ws + 16 * MB);
  f16* Kp = (f16*)(ws + 20 * MB);
  f16* Vb = (f16*)(ws + 21 * MB);
  f16* Wproj = (f16*)(ws + 25 * MB);
  f16* Wcat = (f16*)(ws + 25 * MB + 512 * 1024);
  f16* F = (f16*)(ws + 26 * MB);
  f16* att = F;  // alias: F fully consumed by k_pool before k_flash writes att

  hipLaunchKernelGGL(k_prep_w, dim3(1408), dim3(256), 0, stream, wt, wp, wg, wo, wr, gm,
                     Wproj, Wcat);
  hipLaunchKernelGGL(k_transpose, dim3(4, 64, 8), dim3(256), 0, stream, x, xT);
  hipLaunchKernelGGL(k_gemm_projq, dim3(6, 32, 8), dim3(256), 0, stream, xT, Wproj, Qb, F);
  hipLaunchKernelGGL(k_pool, dim3(320), dim3(256), 0, stream, F, Kp, Vb);
  hipLaunchKernelGGL(k_flash, dim3(64, 8), dim3(512), 0, stream, Qb, Kp, Vb, att);
  hipLaunchKernelGGL(k_gemm_out, dim3(4, 32, 8), dim3(256), 0, stream, Wcat, att, xT, out);
}

// Round 11
// 167.693 us; speedup vs baseline: 1.0315x; 1.0315x over previous
//
#include <hip/hip_runtime.h>

// NonLocalBlock (SAGAN non-local) fused pipeline for MI355X / gfx950.
// B=8, Cin=256, H=W=64 (HW=4096), Cout=512. Workspace (~46 MB of d_ws):
//   [0,16MB)   xT   fp16 [8][4096][256]
//   [16,20MB)  Q    fp16 [8][4096][64]
//   [20,21MB)  Kp   fp16 [8][1024][64]   (8B-half-swapped per key-row bit3)
//   [21,25MB)  V    fp16 [8][256][1024]  (8B-half-swapped per ch-row bit3)
//   [25MB+0)   Wproj fp16 [384][256]; [25MB+512K) Wcat fp16 [512][512]
//   [26,46MB)  F    fp16 [8][320][4096]; att aliases F
//
// R10->R11: R10's key-split spilled (oT 64 AGPR + S + qf > 128-reg cap ->
// +53MB scratch HBM, 66->90us). Reverted to the R9 flash (0 conflicts, no
// spill) and R6 GEMM grid order (R9/R10's mt-fastest swap cost ~10-20us on
// the GEMMs). New: softmax reductions tree-ified — R9 had 31 sequential
// dependent fmax + 32 sequential adds per wave/kt (~250 serial cy); balanced
// trees cut that ~5x (VALU was the limiter: 53% busy, MfmaUtil 20%).

typedef _Float16 f16;
typedef f16 f16x4 __attribute__((ext_vector_type(4)));
typedef f16 f16x8 __attribute__((ext_vector_type(8)));
typedef f16 h2 __attribute__((ext_vector_type(2)));
typedef float f32x4 __attribute__((ext_vector_type(4)));
typedef float f32x16 __attribute__((ext_vector_type(16)));
typedef int int2v __attribute__((ext_vector_type(2)));

#define MFMA16(a, b, c) __builtin_amdgcn_mfma_f32_16x16x32_f16((a), (b), (c), 0, 0, 0)
#define MFMA32(a, b, c) __builtin_amdgcn_mfma_f32_32x32x16_f16((a), (b), (c), 0, 0, 0)

__device__ __forceinline__ void gload16(const void* src, void* dst_lds) {
  __builtin_amdgcn_global_load_lds(
      (const __attribute__((address_space(1))) void*)src,
      (__attribute__((address_space(3))) void*)dst_lds, 16, 0, 0);
}

__device__ __forceinline__ f16x8 cat8(f16x4 a, f16x4 b) {
  f16x8 r;
  r[0] = a[0]; r[1] = a[1]; r[2] = a[2]; r[3] = a[3];
  r[4] = b[0]; r[5] = b[1]; r[6] = b[2]; r[7] = b[3];
  return r;
}

__device__ __forceinline__ h2 pk2(float a, float b) {
  return __builtin_bit_cast(h2, __builtin_amdgcn_cvt_pkrtz(a, b));
}

__device__ __forceinline__ float asf(int x) { return __builtin_bit_cast(float, x); }
__device__ __forceinline__ int asi(float x) { return __builtin_bit_cast(int, x); }

// -------------------------------------------------------------------------
__global__ __launch_bounds__(256, 4)
void k_prep_w(const float* __restrict__ wt, const float* __restrict__ wp,
              const float* __restrict__ wg, const float* __restrict__ wo,
              const float* __restrict__ wr, const float* __restrict__ gamma,
              f16* __restrict__ Wproj, f16* __restrict__ Wcat) {
  int i = blockIdx.x * 256 + threadIdx.x;
  const float s = 0.08838834764831845f;    // sqrt(2/256)
  const float is2 = 0.7071067811865476f;   // 1/sqrt(2)
  if (i < 384 * 256) {
    float v = (i < 64 * 256) ? wt[i]
              : (i < 128 * 256 ? wp[i - 64 * 256] : wg[i - 128 * 256]);
    Wproj[i] = (f16)(v * s);
  } else {
    int j = i - 384 * 256;
    if (j < 512 * 512) {
      int r = j >> 9, c = j & 511;
      float v = (c < 256) ? wo[r * 256 + c] * (gamma[0] * s * is2)
                          : wr[r * 256 + (c - 256)] * (s * is2);
      Wcat[j] = (f16)v;
    }
  }
}

// -------------------------------------------------------------------------
// Transpose x [b][256][4096] fp32 -> xT [b][4096][256] fp16 via 64x64 LDS tiles.
__global__ __launch_bounds__(256, 4)
void k_transpose(const float* __restrict__ x, f16* __restrict__ xT) {
  __shared__ f16 tile[64 * 72];
  int b = blockIdx.z, nt = blockIdx.y, ct = blockIdx.x;
  int t = threadIdx.x;
  {
    int c = t >> 2, nch = (t & 3) * 16;
    const float* src = x + (((size_t)b * 256 + ct * 64 + c) << 12) + nt * 64 + nch;
    float4 v0 = *(const float4*)(src);
    float4 v1 = *(const float4*)(src + 4);
    float4 v2 = *(const float4*)(src + 8);
    float4 v3 = *(const float4*)(src + 12);
    f16x8 a = {(f16)v0.x, (f16)v0.y, (f16)v0.z, (f16)v0.w,
               (f16)v1.x, (f16)v1.y, (f16)v1.z, (f16)v1.w};
    f16x8 bb = {(f16)v2.x, (f16)v2.y, (f16)v2.z, (f16)v2.w,
                (f16)v3.x, (f16)v3.y, (f16)v3.z, (f16)v3.w};
    *(f16x8*)&tile[c * 72 + nch] = a;
    *(f16x8*)&tile[c * 72 + nch + 8] = bb;
  }
  __syncthreads();
  {
    int n = t >> 2, cch = (t & 3) * 16;
    f16 tmp[16];
#pragma unroll
    for (int i = 0; i < 16; i++) tmp[i] = tile[(cch + i) * 72 + n];
    f16x8 a, bb;
#pragma unroll
    for (int i = 0; i < 8; i++) { a[i] = tmp[i]; bb[i] = tmp[8 + i]; }
    f16* dst = xT + (((size_t)b * 4096 + nt * 64 + n) << 8) + ct * 64 + cch;
    *(f16x8*)dst = a;
    *(f16x8*)(dst + 8) = bb;
  }
}

// -------------------------------------------------------------------------
// Merged projection GEMM: out rows = Wproj rows [mt*64, mt*64+64).
// mt==0 -> theta -> Q[b][n][64]; mt>=1 -> phi|g -> F[b][jj][n].
__global__ __launch_bounds__(256, 2)
void k_gemm_projq(const f16* __restrict__ xT, const f16* __restrict__ Wproj,
                  f16* __restrict__ Q, f16* __restrict__ F) {
  __shared__ f16 Alds[64 * 64];
  __shared__ f16 Blds[128 * 64];
  int b = blockIdx.z, mt = blockIdx.y, nt = blockIdx.x;
  int lane = threadIdx.x & 63, wave = threadIdx.x >> 6;
  int wm = wave >> 1, wn = wave & 1;
  f32x4 acc[2][4];
#pragma unroll
  for (int mf = 0; mf < 2; mf++)
#pragma unroll
    for (int nf = 0; nf < 4; nf++) acc[mf][nf] = (f32x4){0, 0, 0, 0};
  const f16* Abase = Wproj + ((mt * 64) << 8);
  const f16* Bbase = xT + (((size_t)b * 4096 + nt * 128) << 8);
  for (int k0 = 0; k0 < 256; k0 += 64) {
    __syncthreads();
#pragma unroll
    for (int i = 0; i < 2; i++) {
      int chunk = i * 256 + threadIdx.x;
      int row = chunk >> 3, cc = chunk & 7, scc = cc ^ (row & 7);
      gload16(Abase + (row << 8) + k0 + scc * 8, (char*)Alds + (i * 256 + wave * 64) * 16);
    }
#pragma unroll
    for (int i = 0; i < 4; i++) {
      int chunk = i * 256 + threadIdx.x;
      int row = chunk >> 3, cc = chunk & 7, scc = cc ^ (row & 7);
      gload16(Bbase + (row << 8) + k0 + scc * 8, (char*)Blds + (i * 256 + wave * 64) * 16);
    }
    __syncthreads();
#pragma unroll
    for (int ks = 0; ks < 2; ks++) {
      int cb = ((lane >> 4) * 8 + ks * 32) * 2;
      f16x8 af[2], bf[4];
#pragma unroll
      for (int mf = 0; mf < 2; mf++) {
        int row = wm * 32 + mf * 16 + (lane & 15);
        af[mf] = *(const f16x8*)((const char*)Alds + row * 128 + (cb ^ ((row & 7) << 4)));
      }
#pragma unroll
      for (int nf = 0; nf < 4; nf++) {
        int row = wn * 64 + nf * 16 + (lane & 15);
        bf[nf] = *(const f16x8*)((const char*)Blds + row * 128 + (cb ^ ((row & 7) << 4)));
      }
#pragma unroll
      for (int mf = 0; mf < 2; mf++)
#pragma unroll
        for (int nf = 0; nf < 4; nf++) acc[mf][nf] = MFMA16(af[mf], bf[nf], acc[mf][nf]);
    }
  }
#pragma unroll
  for (int mf = 0; mf < 2; mf++)
#pragma unroll
    for (int nf = 0; nf < 4; nf++)
#pragma unroll
      for (int r = 0; r < 4; r++) {
        int jl = wm * 32 + mf * 16 + (lane >> 4) * 4 + r;  // 0..63
        int n = nt * 128 + wn * 64 + nf * 16 + (lane & 15);
        f16 v = (f16)acc[mf][nf][r];
        if (mt == 0)
          Q[(((size_t)b * 4096 + n) << 6) + jl] = v;
        else
          F[(((size_t)b * 320 + (mt - 1) * 64 + jl) << 12) + n] = v;
      }
}

// -------------------------------------------------------------------------
// 2x2 maxpool: F[b][jj][4096] -> jj<64: Kp[b][m][jj] (phi), jj>=64: V[b][jj-64][m].
// Kp/V written with the 8B-half swap (row-bit3) for conflict-free flash reads.
__global__ __launch_bounds__(256, 4)
void k_pool(const f16* __restrict__ F, f16* __restrict__ Kp, f16* __restrict__ V) {
  int id = blockIdx.x * 256 + threadIdx.x;  // < 8*320*32 = 81920
  int ph = id & 31;
  int rest = id >> 5;
  int jj = rest % 320;
  int b = rest / 320;
  const f16x8* r0 = (const f16x8*)(F + (((size_t)b * 320 + jj) << 12) + ph * 128);
  const f16x8* r1 = r0 + 8;
  f16 outv[32];
#pragma unroll
  for (int ch = 0; ch < 8; ch++) {
    f16x8 u = r0[ch], v = r1[ch];
#pragma unroll
    for (int p = 0; p < 4; p++) {
      float m1 = fmaxf(fmaxf((float)u[2 * p], (float)u[2 * p + 1]),
                       fmaxf((float)v[2 * p], (float)v[2 * p + 1]));
      outv[ch * 4 + p] = (f16)m1;
    }
  }
  int m0 = ph * 32;
  if (jj < 64) {
#pragma unroll
    for (int p = 0; p < 32; p++) {
      int m = m0 + p;
      int jx = jj ^ ((((m) >> 3) & 1) << 2);
      Kp[((size_t)b * 1024 + m) * 64 + jx] = outv[p];
    }
  } else {
    int c = jj - 64;
    int flip = ((c >> 3) & 1) << 2;
    f16* dst = V + (((size_t)b * 256 + c) << 10) + m0;
#pragma unroll
    for (int c8 = 0; c8 < 4; c8++) {
      f16x8 w;
#pragma unroll
      for (int i = 0; i < 8; i++) w[i] = outv[c8 * 8 + (i ^ flip)];
      *(f16x8*)(dst + c8 * 8) = w;
    }
  }
}

// -------------------------------------------------------------------------
// Flash attention (32x32 swapped QK^T): Q [4096][64], K [1024][64],
// V [256][1024] -> att [n][c]. 512 thr = 8 waves = 2 rg(32q) x 4 cg(64ch).
// P register-resident; conflict-free b64 frag reads; tree-reduced softmax.
__global__ __launch_bounds__(512, 4)
void k_flash(const f16* __restrict__ Q, const f16* __restrict__ Kp,
             const f16* __restrict__ V, f16* __restrict__ att) {
  __shared__ f16 Klds[2][64 * 64];    // [key][ch], 8KB each
  __shared__ f16 Vlds[2][256 * 64];   // [ch][key], 32KB each
  int b = blockIdx.y, qt = blockIdx.x;
  int tid = threadIdx.x;
  int lane = tid & 63, wave = tid >> 6;
  int rg = wave >> 2, cg = wave & 3;   // rowgroup 0..1, chgroup 0..3
  int l31 = lane & 31, h5 = lane >> 5;
  const f16* Kb = Kp + ((size_t)b << 16);
  const f16* Vb = V + ((size_t)b << 18);
  const float L2E = 1.44269504f;

  const f16* Qrow = Q + (((size_t)b * 4096 + qt * 64 + rg * 32 + l31) << 6);
  f16x8 qf[4];
#pragma unroll
  for (int t = 0; t < 4; t++) {
    f16x4 lo = *(const f16x4*)(Qrow + t * 16 + 4 * h5);
    f16x4 hi = *(const f16x4*)(Qrow + t * 16 + 8 + 4 * h5);
    qf[t] = cat8(lo, hi);
  }
  f32x16 o0, o1;
#pragma unroll
  for (int i = 0; i < 16; i++) { o0[i] = 0.f; o1[i] = 0.f; }
  float m = -1e30f, lsum = 0.f;

#define STAGE(bufi, kt)                                                          \
  {                                                                              \
    {                                                                            \
      int chunk = tid;                                                           \
      int row = chunk >> 3, cc = chunk & 7, scc = cc ^ (row & 7);                \
      gload16(Kb + (((kt) * 64 + row) << 6) + scc * 8,                           \
              (char*)&Klds[bufi][0] + chunk * 16);                               \
    }                                                                            \
    _Pragma("unroll") for (int i = 0; i < 4; i++) {                              \
      int chunk = i * 512 + tid;                                                 \
      int row = chunk >> 3, cc = chunk & 7, scc = cc ^ (row & 7);                \
      gload16(Vb + ((size_t)row << 10) + (kt) * 64 + scc * 8,                    \
              (char*)&Vlds[bufi][0] + chunk * 16);                               \
    }                                                                            \
  }

  STAGE(0, 0);
  __syncthreads();
  int buf = 0;
  // read XOR: 16B-slot swizzle (row&7) + 8B-granule descramble (row bit3)
  const int swx = ((l31 & 7) << 4) | (((l31 >> 3) & 1) << 3);
  for (int kt = 0; kt < 16; ++kt) {
    if (kt < 15) STAGE(buf ^ 1, kt + 1);
    // ---- S^T = K Q^T
    f32x16 S0, S1;
#pragma unroll
    for (int i = 0; i < 16; i++) { S0[i] = 0.f; S1[i] = 0.f; }
    const char* Kbase = (const char*)&Klds[buf][0];
#pragma unroll
    for (int t = 0; t < 4; t++) {
      int ob = t * 32 + 8 * h5;
      f16x4 a0 = *(const f16x4*)(Kbase + l31 * 128 + (ob ^ swx));
      f16x4 a1 = *(const f16x4*)(Kbase + l31 * 128 + ((ob + 16) ^ swx));
      S0 = MFMA32(cat8(a0, a1), qf[t], S0);
      f16x4 b0 = *(const f16x4*)(Kbase + (l31 + 32) * 128 + (ob ^ swx));
      f16x4 b1 = *(const f16x4*)(Kbase + (l31 + 32) * 128 + ((ob + 16) ^ swx));
      S1 = MFMA32(cat8(b0, b1), qf[t], S1);
    }
    // ---- lane-local max over 64 keys, balanced tree (depth ~5, v_max3-able)
    float mx;
    {
      float ta[8];
#pragma unroll
      for (int i = 0; i < 8; i++)
        ta[i] = fmaxf(fmaxf(S0[i], S0[i + 8]), fmaxf(S1[i], S1[i + 8]));
      float u0 = fmaxf(ta[0], ta[4]);
      float u1 = fmaxf(ta[1], ta[5]);
      float u2 = fmaxf(ta[2], ta[6]);
      float u3 = fmaxf(ta[3], ta[7]);
      mx = fmaxf(fmaxf(u0, u1), fmaxf(u2, u3));
    }
    int2v pr = __builtin_amdgcn_permlane32_swap(asi(mx), asi(mx), false, false);
    mx = fmaxf(asf(pr[0]), asf(pr[1]));
    if (__any(mx > m + 8.f)) {
      float mnew = fmaxf(m, mx);
      float corr = __builtin_amdgcn_exp2f((m - mnew) * L2E);
      m = mnew;
      lsum *= corr;
#pragma unroll
      for (int reg = 0; reg < 16; reg++) {
        float cr = __shfl(corr, (reg & 3) + 8 * (reg >> 2) + 4 * h5, 64);
        o0[reg] *= cr;
        o1[reg] *= cr;
      }
    }
    // ---- fused exp -> pack -> PV (per 16-key slice t); lp tree-summed
    const char* Vbase = (const char*)&Vlds[buf][0];
    int c0 = cg * 64 + l31;
    float lpt[4];
#pragma unroll
    for (int t = 0; t < 4; t++) {
      float ee[8];
#pragma unroll
      for (int j = 0; j < 8; j++) {
        float sv = (t < 2) ? S0[(t & 1) * 8 + j] : S1[(t & 1) * 8 + j];
        ee[j] = __builtin_amdgcn_exp2f((sv - m) * L2E);
      }
      lpt[t] = ((ee[0] + ee[1]) + (ee[2] + ee[3])) + ((ee[4] + ee[5]) + (ee[6] + ee[7]));
      h2 p0 = pk2(ee[0], ee[1]);
      h2 p1 = pk2(ee[2], ee[3]);
      h2 p2 = pk2(ee[4], ee[5]);
      h2 p3 = pk2(ee[6], ee[7]);
      f16x8 af = {p0[0], p0[1], p1[0], p1[1], p2[0], p2[1], p3[0], p3[1]};
      int ob = t * 32 + 8 * h5;
      __builtin_amdgcn_s_setprio(1);
      f16x4 v0a = *(const f16x4*)(Vbase + c0 * 128 + (ob ^ swx));
      f16x4 v0b = *(const f16x4*)(Vbase + c0 * 128 + ((ob + 16) ^ swx));
      o0 = MFMA32(af, cat8(v0a, v0b), o0);
      f16x4 v1a = *(const f16x4*)(Vbase + (c0 + 32) * 128 + (ob ^ swx));
      f16x4 v1b = *(const f16x4*)(Vbase + (c0 + 32) * 128 + ((ob + 16) ^ swx));
      o1 = MFMA32(af, cat8(v1a, v1b), o1);
      __builtin_amdgcn_s_setprio(0);
    }
    lsum += (lpt[0] + lpt[1]) + (lpt[2] + lpt[3]);
    __syncthreads();
    buf ^= 1;
  }
#undef STAGE
  // final l merge across halves + normalize + store
  int2v pl = __builtin_amdgcn_permlane32_swap(asi(lsum), asi(lsum), false, false);
  float inv = 1.f / (asf(pl[0]) + asf(pl[1]));
  int nbase = qt * 64 + rg * 32;
#pragma unroll
  for (int reg = 0; reg < 16; reg++) {
    int qr = (reg & 3) + 8 * (reg >> 2) + 4 * h5;
    float iv = __shfl(inv, qr, 64);
    f16* dst = att + (((size_t)b * 4096 + nbase + qr) << 8) + cg * 64 + l31;
    dst[0] = (f16)(o0[reg] * iv);
    dst[32] = (f16)(o1[reg] * iv);
  }
}

// -------------------------------------------------------------------------
// Output GEMM: out[b][o][n] = sum_{k<512} Wcat[o][k] * Bcat[n][k], Bcat=[att|xT].
__global__ __launch_bounds__(256, 2)
void k_gemm_out(const f16* __restrict__ Wcat, const f16* __restrict__ att,
                const f16* __restrict__ xT, float* __restrict__ out) {
  __shared__ f16 Alds[128 * 64];
  __shared__ f16 Blds[128 * 64];
  int b = blockIdx.z, mt = blockIdx.y, nt = blockIdx.x;
  int lane = threadIdx.x & 63, wave = threadIdx.x >> 6;
  int wm = wave >> 1, wn = wave & 1;
  f32x4 acc[4][4];
#pragma unroll
  for (int mf = 0; mf < 4; mf++)
#pragma unroll
    for (int nf = 0; nf < 4; nf++) acc[mf][nf] = (f32x4){0, 0, 0, 0};
  const f16* Abase = Wcat + (size_t)(mt * 128) * 512;
  for (int k0 = 0; k0 < 512; k0 += 64) {
    __syncthreads();
#pragma unroll
    for (int i = 0; i < 4; i++) {
      int chunk = i * 256 + threadIdx.x;
      int row = chunk >> 3, cc = chunk & 7, scc = cc ^ (row & 7);
      gload16(Abase + row * 512 + k0 + scc * 8, (char*)Alds + (i * 256 + wave * 64) * 16);
    }
    const f16* Bcol = (k0 < 256) ? (att + (((size_t)b * 4096 + nt * 128) << 8))
                                 : (xT + (((size_t)b * 4096 + nt * 128) << 8));
    int kk = (k0 < 256) ? k0 : (k0 - 256);
#pragma unroll
    for (int i = 0; i < 4; i++) {
      int chunk = i * 256 + threadIdx.x;
      int row = chunk >> 3, cc = chunk & 7, scc = cc ^ (row & 7);
      gload16(Bcol + (row << 8) + kk + scc * 8, (char*)Blds + (i * 256 + wave * 64) * 16);
    }
    __syncthreads();
#pragma unroll
    for (int ks = 0; ks < 2; ks++) {
      int cb = ((lane >> 4) * 8 + ks * 32) * 2;
      f16x8 af[4], bf[4];
#pragma unroll
      for (int mf = 0; mf < 4; mf++) {
        int row = wm * 64 + mf * 16 + (lane & 15);
        af[mf] = *(const f16x8*)((const char*)Alds + row * 128 + (cb ^ ((row & 7) << 4)));
      }
#pragma unroll
      for (int nf = 0; nf < 4; nf++) {
        int row = wn * 64 + nf * 16 + (lane & 15);
        bf[nf] = *(const f16x8*)((const char*)Blds + row * 128 + (cb ^ ((row & 7) << 4)));
      }
#pragma unroll
      for (int mf = 0; mf < 4; mf++)
#pragma unroll
        for (int nf = 0; nf < 4; nf++) acc[mf][nf] = MFMA16(af[mf], bf[nf], acc[mf][nf]);
    }
  }
#pragma unroll
  for (int mf = 0; mf < 4; mf++)
#pragma unroll
    for (int nf = 0; nf < 4; nf++)
#pragma unroll
      for (int r = 0; r < 4; r++) {
        int oo = mt * 128 + wm * 64 + mf * 16 + (lane >> 4) * 4 + r;
        int n = nt * 128 + wn * 64 + nf * 16 + (lane & 15);
        out[(((size_t)b * 512 + oo) << 12) + n] = acc[mf][nf][r];
      }
}

// -------------------------------------------------------------------------
extern "C" void kernel_launch(void* const* d_in, const int* in_sizes, int n_in,
                              void* d_out, int out_size, void* d_ws, size_t ws_size,
                              hipStream_t stream) {
  const float* x = (const float*)d_in[0];
  const float* wt = (const float*)d_in[1];
  const float* wp = (const float*)d_in[2];
  const float* wg = (const float*)d_in[3];
  const float* wo = (const float*)d_in[4];
  const float* wr = (const float*)d_in[5];
  const float* gm = (const float*)d_in[6];
  float* out = (float*)d_out;
  char* ws = (char*)d_ws;
  const size_t MB = 1024 * 1024;
  f16* xT = (f16*)(ws);
  f16* Qb = (f16*)(ws + 16 * MB);
  f16* Kp = (f16*)(ws + 20 * MB);
  f16* Vb = (f16*)(ws + 21 * MB);
  f16* Wproj = (f16*)(ws + 25 * MB);
  f16* Wcat = (f16*)(ws + 25 * MB + 512 * 1024);
  f16* F = (f16*)(ws + 26 * MB);
  f16* att = F;  // alias: F fully consumed by k_pool before k_flash writes att

  hipLaunchKernelGGL(k_prep_w, dim3(1408), dim3(256), 0, stream, wt, wp, wg, wo, wr, gm,
                     Wproj, Wcat);
  hipLaunchKernelGGL(k_transpose, dim3(4, 64, 8), dim3(256), 0, stream, x, xT);
  hipLaunchKernelGGL(k_gemm_projq, dim3(32, 6, 8), dim3(256), 0, stream, xT, Wproj, Qb, F);
  hipLaunchKernelGGL(k_pool, dim3(320), dim3(256), 0, stream, F, Kp, Vb);
  hipLaunchKernelGGL(k_flash, dim3(64, 8), dim3(512), 0, stream, Qb, Kp, Vb, att);
  hipLaunchKernelGGL(k_gemm_out, dim3(32, 4, 8), dim3(256), 0, stream, Wcat, att, xT, out);
}

// Round 12
// 126.842 us; speedup vs baseline: 1.3636x; 1.3221x over previous
//
#include <hip/hip_runtime.h>

// NonLocalBlock (SAGAN non-local) fused pipeline for MI355X / gfx950.
// B=8, Cin=256, H=W=64 (HW=4096), Cout=512. Workspace (~46 MB of d_ws):
//   [0,16MB)   xT   fp16 [8][4096][256]
//   [16,20MB)  Q    fp16 [8][4096][64]
//   [20,21MB)  Kp   fp16 [8][1024][64]
//   [21,25MB)  V    fp16 [8][256][1024]
//   [25MB+0)   Wproj fp16 [384][256]; [25MB+512K) Wcat fp16 [512][512]
//   [26,46MB)  F    fp16 [8][320][4096]; att aliases F
//
// R11->R12: re-anchor on the best measured config = exact R6 (136us total):
// unscrambled k_pool, R6 grids, 16x16 swapped-QK^T flash (92 VGPR, no spill).
// Cross-round evidence: every config carrying the scrambled-pool producers
// (R8/R9/R11) paid +11-13us in the non-flash kernels — more than the 32x32
// flash ever saved. Single zero-risk upgrade here: exp2f (libm, extra range-
// handling VALU) -> __builtin_amdgcn_exp2f (raw v_exp_f32) in the flash
// softmax, which is VALU-limited (VALUBusy 37%, MfmaUtil 14%).

typedef _Float16 f16;
typedef f16 f16x4 __attribute__((ext_vector_type(4)));
typedef f16 f16x8 __attribute__((ext_vector_type(8)));
typedef float f32x4 __attribute__((ext_vector_type(4)));

#define MFMA16(a, b, c) __builtin_amdgcn_mfma_f32_16x16x32_f16((a), (b), (c), 0, 0, 0)

__device__ __forceinline__ void gload16(const void* src, void* dst_lds) {
  __builtin_amdgcn_global_load_lds(
      (const __attribute__((address_space(1))) void*)src,
      (__attribute__((address_space(3))) void*)dst_lds, 16, 0, 0);
}

// -------------------------------------------------------------------------
__global__ __launch_bounds__(256, 4)
void k_prep_w(const float* __restrict__ wt, const float* __restrict__ wp,
              const float* __restrict__ wg, const float* __restrict__ wo,
              const float* __restrict__ wr, const float* __restrict__ gamma,
              f16* __restrict__ Wproj, f16* __restrict__ Wcat) {
  int i = blockIdx.x * 256 + threadIdx.x;
  const float s = 0.08838834764831845f;    // sqrt(2/256)
  const float is2 = 0.7071067811865476f;   // 1/sqrt(2)
  if (i < 384 * 256) {
    float v = (i < 64 * 256) ? wt[i]
              : (i < 128 * 256 ? wp[i - 64 * 256] : wg[i - 128 * 256]);
    Wproj[i] = (f16)(v * s);
  } else {
    int j = i - 384 * 256;
    if (j < 512 * 512) {
      int r = j >> 9, c = j & 511;
      float v = (c < 256) ? wo[r * 256 + c] * (gamma[0] * s * is2)
                          : wr[r * 256 + (c - 256)] * (s * is2);
      Wcat[j] = (f16)v;
    }
  }
}

// -------------------------------------------------------------------------
// Transpose x [b][256][4096] fp32 -> xT [b][4096][256] fp16 via 64x64 LDS tiles.
__global__ __launch_bounds__(256, 4)
void k_transpose(const float* __restrict__ x, f16* __restrict__ xT) {
  __shared__ f16 tile[64 * 72];
  int b = blockIdx.z, nt = blockIdx.y, ct = blockIdx.x;
  int t = threadIdx.x;
  {
    int c = t >> 2, nch = (t & 3) * 16;
    const float* src = x + (((size_t)b * 256 + ct * 64 + c) << 12) + nt * 64 + nch;
    float4 v0 = *(const float4*)(src);
    float4 v1 = *(const float4*)(src + 4);
    float4 v2 = *(const float4*)(src + 8);
    float4 v3 = *(const float4*)(src + 12);
    f16x8 a = {(f16)v0.x, (f16)v0.y, (f16)v0.z, (f16)v0.w,
               (f16)v1.x, (f16)v1.y, (f16)v1.z, (f16)v1.w};
    f16x8 bb = {(f16)v2.x, (f16)v2.y, (f16)v2.z, (f16)v2.w,
                (f16)v3.x, (f16)v3.y, (f16)v3.z, (f16)v3.w};
    *(f16x8*)&tile[c * 72 + nch] = a;
    *(f16x8*)&tile[c * 72 + nch + 8] = bb;
  }
  __syncthreads();
  {
    int n = t >> 2, cch = (t & 3) * 16;
    f16 tmp[16];
#pragma unroll
    for (int i = 0; i < 16; i++) tmp[i] = tile[(cch + i) * 72 + n];
    f16x8 a, bb;
#pragma unroll
    for (int i = 0; i < 8; i++) { a[i] = tmp[i]; bb[i] = tmp[8 + i]; }
    f16* dst = xT + (((size_t)b * 4096 + nt * 64 + n) << 8) + ct * 64 + cch;
    *(f16x8*)dst = a;
    *(f16x8*)(dst + 8) = bb;
  }
}

// -------------------------------------------------------------------------
// Merged projection GEMM: out rows = Wproj rows [mt*64, mt*64+64).
// mt==0 -> theta -> Q[b][n][64]; mt>=1 -> phi|g -> F[b][jj][n].
__global__ __launch_bounds__(256, 2)
void k_gemm_projq(const f16* __restrict__ xT, const f16* __restrict__ Wproj,
                  f16* __restrict__ Q, f16* __restrict__ F) {
  __shared__ f16 Alds[64 * 64];
  __shared__ f16 Blds[128 * 64];
  int b = blockIdx.z, mt = blockIdx.y, nt = blockIdx.x;
  int lane = threadIdx.x & 63, wave = threadIdx.x >> 6;
  int wm = wave >> 1, wn = wave & 1;
  f32x4 acc[2][4];
#pragma unroll
  for (int mf = 0; mf < 2; mf++)
#pragma unroll
    for (int nf = 0; nf < 4; nf++) acc[mf][nf] = (f32x4){0, 0, 0, 0};
  const f16* Abase = Wproj + ((mt * 64) << 8);
  const f16* Bbase = xT + (((size_t)b * 4096 + nt * 128) << 8);
  for (int k0 = 0; k0 < 256; k0 += 64) {
    __syncthreads();
#pragma unroll
    for (int i = 0; i < 2; i++) {
      int chunk = i * 256 + threadIdx.x;
      int row = chunk >> 3, cc = chunk & 7, scc = cc ^ (row & 7);
      gload16(Abase + (row << 8) + k0 + scc * 8, (char*)Alds + (i * 256 + wave * 64) * 16);
    }
#pragma unroll
    for (int i = 0; i < 4; i++) {
      int chunk = i * 256 + threadIdx.x;
      int row = chunk >> 3, cc = chunk & 7, scc = cc ^ (row & 7);
      gload16(Bbase + (row << 8) + k0 + scc * 8, (char*)Blds + (i * 256 + wave * 64) * 16);
    }
    __syncthreads();
#pragma unroll
    for (int ks = 0; ks < 2; ks++) {
      int cb = ((lane >> 4) * 8 + ks * 32) * 2;
      f16x8 af[2], bf[4];
#pragma unroll
      for (int mf = 0; mf < 2; mf++) {
        int row = wm * 32 + mf * 16 + (lane & 15);
        af[mf] = *(const f16x8*)((const char*)Alds + row * 128 + (cb ^ ((row & 7) << 4)));
      }
#pragma unroll
      for (int nf = 0; nf < 4; nf++) {
        int row = wn * 64 + nf * 16 + (lane & 15);
        bf[nf] = *(const f16x8*)((const char*)Blds + row * 128 + (cb ^ ((row & 7) << 4)));
      }
#pragma unroll
      for (int mf = 0; mf < 2; mf++)
#pragma unroll
        for (int nf = 0; nf < 4; nf++) acc[mf][nf] = MFMA16(af[mf], bf[nf], acc[mf][nf]);
    }
  }
#pragma unroll
  for (int mf = 0; mf < 2; mf++)
#pragma unroll
    for (int nf = 0; nf < 4; nf++)
#pragma unroll
      for (int r = 0; r < 4; r++) {
        int jl = wm * 32 + mf * 16 + (lane >> 4) * 4 + r;  // 0..63
        int n = nt * 128 + wn * 64 + nf * 16 + (lane & 15);
        f16 v = (f16)acc[mf][nf][r];
        if (mt == 0)
          Q[(((size_t)b * 4096 + n) << 6) + jl] = v;
        else
          F[(((size_t)b * 320 + (mt - 1) * 64 + jl) << 12) + n] = v;
      }
}

// -------------------------------------------------------------------------
// 2x2 maxpool: F[b][jj][4096] -> jj<64: Kp[b][m][jj] (phi), jj>=64: V[b][jj-64][m].
__global__ __launch_bounds__(256, 4)
void k_pool(const f16* __restrict__ F, f16* __restrict__ Kp, f16* __restrict__ V) {
  int id = blockIdx.x * 256 + threadIdx.x;  // < 8*320*32 = 81920
  int ph = id & 31;
  int rest = id >> 5;
  int jj = rest % 320;
  int b = rest / 320;
  const f16x8* r0 = (const f16x8*)(F + (((size_t)b * 320 + jj) << 12) + ph * 128);
  const f16x8* r1 = r0 + 8;
  f16 outv[32];
#pragma unroll
  for (int ch = 0; ch < 8; ch++) {
    f16x8 u = r0[ch], v = r1[ch];
#pragma unroll
    for (int p = 0; p < 4; p++) {
      float m1 = fmaxf(fmaxf((float)u[2 * p], (float)u[2 * p + 1]),
                       fmaxf((float)v[2 * p], (float)v[2 * p + 1]));
      outv[ch * 4 + p] = (f16)m1;
    }
  }
  int m0 = ph * 32;
  if (jj < 64) {
#pragma unroll
    for (int p = 0; p < 32; p++)
      Kp[((size_t)b * 1024 + m0 + p) * 64 + jj] = outv[p];
  } else {
    f16* dst = V + (((size_t)b * 256 + (jj - 64)) << 10) + m0;
#pragma unroll
    for (int c8 = 0; c8 < 4; c8++) {
      f16x8 w;
#pragma unroll
      for (int i = 0; i < 8; i++) w[i] = outv[c8 * 8 + i];
      *(f16x8*)(dst + c8 * 8) = w;
    }
  }
}

// -------------------------------------------------------------------------
// Flash attention, swapped-QK^T (16x16): Q [4096][64], K [1024][64],
// V [256][1024] -> att [n][c]. 512 thr = 8 waves = 4 rg(32q) x 2 cg(128ch).
// s = MFMA(kf, qf): lane (hi,l15) holds q-row l15 (per h-half), keys
// mf*16+hi*4+r -> lane-local softmax; P packed f16x4 -> wave-private LDS.
__global__ __launch_bounds__(512, 2)
void k_flash(const f16* __restrict__ Q, const f16* __restrict__ Kp,
             const f16* __restrict__ V, f16* __restrict__ att) {
  __shared__ f16 Klds[2][64 * 64];    // [key][ch] swizzled, 8KB each
  __shared__ f16 Vlds[2][256 * 64];   // [ch][key] swizzled, 32KB each
  __shared__ f16 Plds[8][32 * 72];    // per-wave P [q][key], 144B rows
  int b = blockIdx.y, qt = blockIdx.x;
  int tid = threadIdx.x;
  int lane = tid & 63, wave = tid >> 6;   // 8 waves
  int rg = wave >> 1, cg2 = wave & 1;     // row-group 0..3, channel-group 0..1
  int l15 = lane & 15, hi = lane >> 4;
  const f16* Kb = Kp + ((size_t)b << 16);
  const f16* Vb = V + ((size_t)b << 18);
  f16* Pw = &Plds[wave][0];
  const float L2E = 1.44269504f;
  // Q fragments: rows qt*128 + rg*32 + h*16 + l15
  f16x8 qf[2][2];
#pragma unroll
  for (int h = 0; h < 2; h++)
#pragma unroll
    for (int ks = 0; ks < 2; ks++)
      qf[h][ks] = *(const f16x8*)(
          Q + (((size_t)b * 4096 + qt * 128 + rg * 32 + h * 16 + l15) << 6) +
          ks * 32 + hi * 8);
  f32x4 o[2][8];
#pragma unroll
  for (int h = 0; h < 2; h++)
#pragma unroll
    for (int i = 0; i < 8; i++) o[h][i] = (f32x4){0, 0, 0, 0};
  float mrow[2] = {-1e30f, -1e30f};
  float lrow[2] = {0.f, 0.f};

  int cbase = hi * 16;  // byte offset of this lane's 16B k-chunk within a 128B row

#define STAGE(bufi, kt)                                                          \
  {                                                                              \
    {                                                                            \
      int chunk = tid;                                                           \
      int row = chunk >> 3, cc = chunk & 7, scc = cc ^ (row & 7);                \
      gload16(Kb + (((kt) * 64 + row) << 6) + scc * 8,                           \
              (char*)&Klds[bufi][0] + chunk * 16);                               \
    }                                                                            \
    _Pragma("unroll") for (int i = 0; i < 4; i++) {                              \
      int chunk = i * 512 + tid;                                                 \
      int row = chunk >> 3, cc = chunk & 7, scc = cc ^ (row & 7);                \
      gload16(Vb + ((size_t)row << 10) + (kt) * 64 + scc * 8,                    \
              (char*)&Vlds[bufi][0] + chunk * 16);                               \
    }                                                                            \
  }

  STAGE(0, 0);
  __syncthreads();
  int buf = 0;
  for (int kt = 0; kt < 16; ++kt) {
    if (kt < 15) STAGE(buf ^ 1, kt + 1);
    // ---- S^T = K Q^T: lane holds q-row l15 (h-half), keys mf*16+hi*4+r
    f32x4 s[2][4];
#pragma unroll
    for (int h = 0; h < 2; h++)
#pragma unroll
      for (int mf = 0; mf < 4; mf++) s[h][mf] = (f32x4){0, 0, 0, 0};
#pragma unroll
    for (int ks = 0; ks < 2; ks++) {
      f16x8 kf[4];
#pragma unroll
      for (int mf = 0; mf < 4; mf++) {
        int row = mf * 16 + l15;
        kf[mf] = *(const f16x8*)((const char*)&Klds[buf][0] + row * 128 +
                                 ((cbase + ks * 64) ^ ((row & 7) << 4)));
      }
#pragma unroll
      for (int h = 0; h < 2; h++)
#pragma unroll
        for (int mf = 0; mf < 4; mf++)
          s[h][mf] = MFMA16(kf[mf], qf[h][ks], s[h][mf]);
    }
    // ---- lane-local online softmax (defer-max THR=8)
    float pmax[2];
#pragma unroll
    for (int h = 0; h < 2; h++) {
      float t0 = fmaxf(fmaxf(s[h][0][0], s[h][1][0]), fmaxf(s[h][2][0], s[h][3][0]));
      float t1 = fmaxf(fmaxf(s[h][0][1], s[h][1][1]), fmaxf(s[h][2][1], s[h][3][1]));
      float t2 = fmaxf(fmaxf(s[h][0][2], s[h][1][2]), fmaxf(s[h][2][2], s[h][3][2]));
      float t3 = fmaxf(fmaxf(s[h][0][3], s[h][1][3]), fmaxf(s[h][2][3], s[h][3][3]));
      float mx = fmaxf(fmaxf(t0, t1), fmaxf(t2, t3));
      mx = fmaxf(mx, __shfl_xor(mx, 16, 64));
      mx = fmaxf(mx, __shfl_xor(mx, 32, 64));
      pmax[h] = mx;
    }
    bool need = (pmax[0] > mrow[0] + 8.f) || (pmax[1] > mrow[1] + 8.f);
    if (__any(need)) {
#pragma unroll
      for (int h = 0; h < 2; h++) {
        float mnew = fmaxf(mrow[h], pmax[h]);
        float corr = __builtin_amdgcn_exp2f((mrow[h] - mnew) * L2E);
        lrow[h] *= corr;
        mrow[h] = mnew;
#pragma unroll
        for (int r = 0; r < 4; r++) {
          float cr = __shfl(corr, (hi << 4) + (hi << 2) + r, 64);
#pragma unroll
          for (int cf = 0; cf < 8; cf++) o[h][cf][r] *= cr;
        }
      }
    }
#pragma unroll
    for (int h = 0; h < 2; h++) {
      float e[4][4];
#pragma unroll
      for (int mf = 0; mf < 4; mf++)
#pragma unroll
        for (int r = 0; r < 4; r++)
          e[mf][r] = __builtin_amdgcn_exp2f((s[h][mf][r] - mrow[h]) * L2E);
      // pack & store P row (key k = mf*16 + hi*4 + r at byte k*2)
#pragma unroll
      for (int mf = 0; mf < 4; mf++) {
        f16x4 w = {(f16)e[mf][0], (f16)e[mf][1], (f16)e[mf][2], (f16)e[mf][3]};
        *(f16x4*)((char*)Pw + (h * 16 + l15) * 144 + mf * 32 + hi * 8) = w;
      }
      float u0 = (e[0][0] + e[1][0]) + (e[2][0] + e[3][0]);
      float u1 = (e[0][1] + e[1][1]) + (e[2][1] + e[3][1]);
      float u2 = (e[0][2] + e[1][2]) + (e[2][2] + e[3][2]);
      float u3 = (e[0][3] + e[1][3]) + (e[2][3] + e[3][3]);
      float sum = (u0 + u1) + (u2 + u3);
      sum += __shfl_xor(sum, 16, 64);
      sum += __shfl_xor(sum, 32, 64);
      lrow[h] += sum;
    }
    // ---- PV: this wave covers channels cg2*128 .. cg2*128+127
#pragma unroll
    for (int ks = 0; ks < 2; ks++) {
      f16x8 af[2];
#pragma unroll
      for (int h = 0; h < 2; h++)
        af[h] = *(const f16x8*)((char*)Pw + (h * 16 + l15) * 144 + ks * 64 + hi * 16);
      __builtin_amdgcn_s_setprio(1);
#pragma unroll
      for (int cg = 0; cg < 2; cg++) {
        f16x8 vf[4];
#pragma unroll
        for (int u = 0; u < 4; u++) {
          int row = (cg2 * 8 + cg * 4 + u) * 16 + l15;
          vf[u] = *(const f16x8*)((const char*)&Vlds[buf][0] + row * 128 +
                                  ((cbase + ks * 64) ^ ((row & 7) << 4)));
        }
#pragma unroll
        for (int h = 0; h < 2; h++)
#pragma unroll
          for (int u = 0; u < 4; u++)
            o[h][cg * 4 + u] = MFMA16(af[h], vf[u], o[h][cg * 4 + u]);
      }
      __builtin_amdgcn_s_setprio(0);
    }
    __syncthreads();
    buf ^= 1;
  }
#undef STAGE
  int nbase = qt * 128 + rg * 32 + hi * 4;
#pragma unroll
  for (int h = 0; h < 2; h++) {
    float inv = 1.f / lrow[h];
#pragma unroll
    for (int r = 0; r < 4; r++) {
      float iv = __shfl(inv, (hi << 4) + (hi << 2) + r, 64);
#pragma unroll
      for (int cf = 0; cf < 8; cf++) {
        int n = nbase + h * 16 + r;
        int c = cg2 * 128 + cf * 16 + l15;
        att[(((size_t)b * 4096 + n) << 8) + c] = (f16)(o[h][cf][r] * iv);
      }
    }
  }
}

// -------------------------------------------------------------------------
// Output GEMM: out[b][o][n] = sum_{k<512} Wcat[o][k] * Bcat[n][k], Bcat=[att|xT].
__global__ __launch_bounds__(256, 2)
void k_gemm_out(const f16* __restrict__ Wcat, const f16* __restrict__ att,
                const f16* __restrict__ xT, float* __restrict__ out) {
  __shared__ f16 Alds[128 * 64];
  __shared__ f16 Blds[128 * 64];
  int b = blockIdx.z, mt = blockIdx.y, nt = blockIdx.x;
  int lane = threadIdx.x & 63, wave = threadIdx.x >> 6;
  int wm = wave >> 1, wn = wave & 1;
  f32x4 acc[4][4];
#pragma unroll
  for (int mf = 0; mf < 4; mf++)
#pragma unroll
    for (int nf = 0; nf < 4; nf++) acc[mf][nf] = (f32x4){0, 0, 0, 0};
  const f16* Abase = Wcat + (size_t)(mt * 128) * 512;
  for (int k0 = 0; k0 < 512; k0 += 64) {
    __syncthreads();
#pragma unroll
    for (int i = 0; i < 4; i++) {
      int chunk = i * 256 + threadIdx.x;
      int row = chunk >> 3, cc = chunk & 7, scc = cc ^ (row & 7);
      gload16(Abase + row * 512 + k0 + scc * 8, (char*)Alds + (i * 256 + wave * 64) * 16);
    }
    const f16* Bcol = (k0 < 256) ? (att + (((size_t)b * 4096 + nt * 128) << 8))
                                 : (xT + (((size_t)b * 4096 + nt * 128) << 8));
    int kk = (k0 < 256) ? k0 : (k0 - 256);
#pragma unroll
    for (int i = 0; i < 4; i++) {
      int chunk = i * 256 + threadIdx.x;
      int row = chunk >> 3, cc = chunk & 7, scc = cc ^ (row & 7);
      gload16(Bcol + (row << 8) + kk + scc * 8, (char*)Blds + (i * 256 + wave * 64) * 16);
    }
    __syncthreads();
#pragma unroll
    for (int ks = 0; ks < 2; ks++) {
      int cb = ((lane >> 4) * 8 + ks * 32) * 2;
      f16x8 af[4], bf[4];
#pragma unroll
      for (int mf = 0; mf < 4; mf++) {
        int row = wm * 64 + mf * 16 + (lane & 15);
        af[mf] = *(const f16x8*)((const char*)Alds + row * 128 + (cb ^ ((row & 7) << 4)));
      }
#pragma unroll
      for (int nf = 0; nf < 4; nf++) {
        int row = wn * 64 + nf * 16 + (lane & 15);
        bf[nf] = *(const f16x8*)((const char*)Blds + row * 128 + (cb ^ ((row & 7) << 4)));
      }
#pragma unroll
      for (int mf = 0; mf < 4; mf++)
#pragma unroll
        for (int nf = 0; nf < 4; nf++) acc[mf][nf] = MFMA16(af[mf], bf[nf], acc[mf][nf]);
    }
  }
#pragma unroll
  for (int mf = 0; mf < 4; mf++)
#pragma unroll
    for (int nf = 0; nf < 4; nf++)
#pragma unroll
      for (int r = 0; r < 4; r++) {
        int oo = mt * 128 + wm * 64 + mf * 16 + (lane >> 4) * 4 + r;
        int n = nt * 128 + wn * 64 + nf * 16 + (lane & 15);
        out[(((size_t)b * 512 + oo) << 12) + n] = acc[mf][nf][r];
      }
}

// -------------------------------------------------------------------------
extern "C" void kernel_launch(void* const* d_in, const int* in_sizes, int n_in,
                              void* d_out, int out_size, void* d_ws, size_t ws_size,
                              hipStream_t stream) {
  const float* x = (const float*)d_in[0];
  const float* wt = (const float*)d_in[1];
  const float* wp = (const float*)d_in[2];
  const float* wg = (const float*)d_in[3];
  const float* wo = (const float*)d_in[4];
  const float* wr = (const float*)d_in[5];
  const float* gm = (const float*)d_in[6];
  float* out = (float*)d_out;
  char* ws = (char*)d_ws;
  const size_t MB = 1024 * 1024;
  f16* xT = (f16*)(ws);
  f16* Qb = (f16*)(ws + 16 * MB);
  f16* Kp = (f16*)(ws + 20 * MB);
  f16* Vb = (f16*)(ws + 21 * MB);
  f16* Wproj = (f16*)(ws + 25 * MB);
  f16* Wcat = (f16*)(ws + 25 * MB + 512 * 1024);
  f16* F = (f16*)(ws + 26 * MB);
  f16* att = F;  // alias: F fully consumed by k_pool before k_flash writes att

  hipLaunchKernelGGL(k_prep_w, dim3(1408), dim3(256), 0, stream, wt, wp, wg, wo, wr, gm,
                     Wproj, Wcat);
  hipLaunchKernelGGL(k_transpose, dim3(4, 64, 8), dim3(256), 0, stream, x, xT);
  hipLaunchKernelGGL(k_gemm_projq, dim3(32, 6, 8), dim3(256), 0, stream, xT, Wproj, Qb, F);
  hipLaunchKernelGGL(k_pool, dim3(320), dim3(256), 0, stream, F, Kp, Vb);
  hipLaunchKernelGGL(k_flash, dim3(32, 8), dim3(512), 0, stream, Qb, Kp, Vb, att);
  hipLaunchKernelGGL(k_gemm_out, dim3(32, 4, 8), dim3(256), 0, stream, Wcat, att, xT, out);
}

// Round 13
// 107.703 us; speedup vs baseline: 1.6060x; 1.1777x over previous
//
#include <hip/hip_runtime.h>

// NonLocalBlock (SAGAN non-local) fused pipeline for MI355X / gfx950.
// B=8, Cin=256, H=W=64 (HW=4096), Cout=512. Workspace (~46 MB of d_ws):
//   [0,16MB)   xT   fp16 [8][4096][256]
//   [16,20MB)  Q    fp16 [8][4096][64]
//   [20,21MB)  Kp   fp16 [8][1024][64]
//   [21,25MB)  V    fp16 [8][256][1024]
//   [25MB+0)   Wproj fp16 [384][256]; [25MB+512K) Wcat fp16 [512][512]
//   [26,42MB)  att  fp16 [8][4096][256]  (F buffer eliminated this round)
//
// R12->R13: single change — fuse the 2x2 maxpool into k_gemm_projq's
// epilogue. A projq tile (64ch x 128n) covers spatial rows {2nt, 2nt+1} x
// all w, so every pool window is block-local: stage tile to LDS ([64][132]
// pad, 2-way banks = free), barrier, max 4 neighbors, write Kp/V directly.
// Kills F entirely (20MB write + 20MB read) and the k_pool launch. Flash
// untouched (R12 anchor: 54.5us, VGPR 88, no spill).

typedef _Float16 f16;
typedef f16 f16x2 __attribute__((ext_vector_type(2)));
typedef f16 f16x4 __attribute__((ext_vector_type(4)));
typedef f16 f16x8 __attribute__((ext_vector_type(8)));
typedef float f32x4 __attribute__((ext_vector_type(4)));

#define MFMA16(a, b, c) __builtin_amdgcn_mfma_f32_16x16x32_f16((a), (b), (c), 0, 0, 0)

__device__ __forceinline__ void gload16(const void* src, void* dst_lds) {
  __builtin_amdgcn_global_load_lds(
      (const __attribute__((address_space(1))) void*)src,
      (__attribute__((address_space(3))) void*)dst_lds, 16, 0, 0);
}

// -------------------------------------------------------------------------
__global__ __launch_bounds__(256, 4)
void k_prep_w(const float* __restrict__ wt, const float* __restrict__ wp,
              const float* __restrict__ wg, const float* __restrict__ wo,
              const float* __restrict__ wr, const float* __restrict__ gamma,
              f16* __restrict__ Wproj, f16* __restrict__ Wcat) {
  int i = blockIdx.x * 256 + threadIdx.x;
  const float s = 0.08838834764831845f;    // sqrt(2/256)
  const float is2 = 0.7071067811865476f;   // 1/sqrt(2)
  if (i < 384 * 256) {
    float v = (i < 64 * 256) ? wt[i]
              : (i < 128 * 256 ? wp[i - 64 * 256] : wg[i - 128 * 256]);
    Wproj[i] = (f16)(v * s);
  } else {
    int j = i - 384 * 256;
    if (j < 512 * 512) {
      int r = j >> 9, c = j & 511;
      float v = (c < 256) ? wo[r * 256 + c] * (gamma[0] * s * is2)
                          : wr[r * 256 + (c - 256)] * (s * is2);
      Wcat[j] = (f16)v;
    }
  }
}

// -------------------------------------------------------------------------
// Transpose x [b][256][4096] fp32 -> xT [b][4096][256] fp16 via 64x64 LDS tiles.
__global__ __launch_bounds__(256, 4)
void k_transpose(const float* __restrict__ x, f16* __restrict__ xT) {
  __shared__ f16 tile[64 * 72];
  int b = blockIdx.z, nt = blockIdx.y, ct = blockIdx.x;
  int t = threadIdx.x;
  {
    int c = t >> 2, nch = (t & 3) * 16;
    const float* src = x + (((size_t)b * 256 + ct * 64 + c) << 12) + nt * 64 + nch;
    float4 v0 = *(const float4*)(src);
    float4 v1 = *(const float4*)(src + 4);
    float4 v2 = *(const float4*)(src + 8);
    float4 v3 = *(const float4*)(src + 12);
    f16x8 a = {(f16)v0.x, (f16)v0.y, (f16)v0.z, (f16)v0.w,
               (f16)v1.x, (f16)v1.y, (f16)v1.z, (f16)v1.w};
    f16x8 bb = {(f16)v2.x, (f16)v2.y, (f16)v2.z, (f16)v2.w,
                (f16)v3.x, (f16)v3.y, (f16)v3.z, (f16)v3.w};
    *(f16x8*)&tile[c * 72 + nch] = a;
    *(f16x8*)&tile[c * 72 + nch + 8] = bb;
  }
  __syncthreads();
  {
    int n = t >> 2, cch = (t & 3) * 16;
    f16 tmp[16];
#pragma unroll
    for (int i = 0; i < 16; i++) tmp[i] = tile[(cch + i) * 72 + n];
    f16x8 a, bb;
#pragma unroll
    for (int i = 0; i < 8; i++) { a[i] = tmp[i]; bb[i] = tmp[8 + i]; }
    f16* dst = xT + (((size_t)b * 4096 + nt * 64 + n) << 8) + ct * 64 + cch;
    *(f16x8*)dst = a;
    *(f16x8*)(dst + 8) = bb;
  }
}

// -------------------------------------------------------------------------
// Merged projection GEMM + fused 2x2 maxpool epilogue.
// Rows = Wproj rows [mt*64, mt*64+64). mt==0 -> theta -> Q[b][n][64].
// mt==1 -> phi -> pool -> Kp[b][m][64]. mt>=2 -> g -> pool -> V[b][ch][m].
__global__ __launch_bounds__(256, 2)
void k_gemm_projq(const f16* __restrict__ xT, const f16* __restrict__ Wproj,
                  f16* __restrict__ Q, f16* __restrict__ Kp, f16* __restrict__ V) {
  __shared__ f16 lds[192 * 64];  // Alds [64*64] | Blds [128*64]; pool aliases
  f16* Alds = lds;
  f16* Blds = lds + 64 * 64;
  int b = blockIdx.z, mt = blockIdx.y, nt = blockIdx.x;
  int tid = threadIdx.x;
  int lane = tid & 63, wave = tid >> 6;
  int wm = wave >> 1, wn = wave & 1;
  int l15 = lane & 15, hi = lane >> 4;
  f32x4 acc[2][4];
#pragma unroll
  for (int mf = 0; mf < 2; mf++)
#pragma unroll
    for (int nf = 0; nf < 4; nf++) acc[mf][nf] = (f32x4){0, 0, 0, 0};
  const f16* Abase = Wproj + ((mt * 64) << 8);
  const f16* Bbase = xT + (((size_t)b * 4096 + nt * 128) << 8);
  for (int k0 = 0; k0 < 256; k0 += 64) {
    __syncthreads();
#pragma unroll
    for (int i = 0; i < 2; i++) {
      int chunk = i * 256 + tid;
      int row = chunk >> 3, cc = chunk & 7, scc = cc ^ (row & 7);
      gload16(Abase + (row << 8) + k0 + scc * 8, (char*)Alds + (i * 256 + wave * 64) * 16);
    }
#pragma unroll
    for (int i = 0; i < 4; i++) {
      int chunk = i * 256 + tid;
      int row = chunk >> 3, cc = chunk & 7, scc = cc ^ (row & 7);
      gload16(Bbase + (row << 8) + k0 + scc * 8, (char*)Blds + (i * 256 + wave * 64) * 16);
    }
    __syncthreads();
#pragma unroll
    for (int ks = 0; ks < 2; ks++) {
      int cb = (hi * 8 + ks * 32) * 2;
      f16x8 af[2], bf[4];
#pragma unroll
      for (int mf = 0; mf < 2; mf++) {
        int row = wm * 32 + mf * 16 + l15;
        af[mf] = *(const f16x8*)((const char*)Alds + row * 128 + (cb ^ ((row & 7) << 4)));
      }
#pragma unroll
      for (int nf = 0; nf < 4; nf++) {
        int row = wn * 64 + nf * 16 + l15;
        bf[nf] = *(const f16x8*)((const char*)Blds + row * 128 + (cb ^ ((row & 7) << 4)));
      }
#pragma unroll
      for (int mf = 0; mf < 2; mf++)
#pragma unroll
        for (int nf = 0; nf < 4; nf++) acc[mf][nf] = MFMA16(af[mf], bf[nf], acc[mf][nf]);
    }
  }
  if (mt == 0) {
    // theta -> Q[b][n][64]
#pragma unroll
    for (int mf = 0; mf < 2; mf++)
#pragma unroll
      for (int nf = 0; nf < 4; nf++)
#pragma unroll
        for (int r = 0; r < 4; r++) {
          int jl = wm * 32 + mf * 16 + hi * 4 + r;
          int n = nt * 128 + wn * 64 + nf * 16 + l15;
          Q[(((size_t)b * 4096 + n) << 6) + jl] = (f16)acc[mf][nf][r];
        }
  } else {
    // stage tile to LDS [64ch][132] (pad -> conflict-free), then 2x2 pool.
    __syncthreads();  // done reading Alds/Blds
    f16* Pool = lds;
#pragma unroll
    for (int mf = 0; mf < 2; mf++)
#pragma unroll
      for (int nf = 0; nf < 4; nf++)
#pragma unroll
        for (int r = 0; r < 4; r++) {
          int jl = wm * 32 + mf * 16 + hi * 4 + r;
          int col = wn * 64 + nf * 16 + l15;
          Pool[jl * 132 + col] = (f16)acc[mf][nf][r];
        }
    __syncthreads();
    // pooled outputs: 64 ch x 32 m (m = nt*32 + j); window = cols {2j,2j+1,64+2j,64+2j+1}
    if (mt == 1) {
      // phi -> Kp[b][m][ch]: thread = (m_l = tid>>3, jj8 = (tid&7)*8)
      int m_l = tid >> 3;
      int jj8 = (tid & 7) * 8;
      f16x8 w;
#pragma unroll
      for (int i = 0; i < 8; i++) {
        int jj = jj8 + i;
        f16x2 p0 = *(const f16x2*)&Pool[jj * 132 + 2 * m_l];
        f16x2 p1 = *(const f16x2*)&Pool[jj * 132 + 64 + 2 * m_l];
        float v = fmaxf(fmaxf((float)p0[0], (float)p0[1]),
                        fmaxf((float)p1[0], (float)p1[1]));
        w[i] = (f16)v;
      }
      *(f16x8*)&Kp[((size_t)b * 1024 + nt * 32 + m_l) * 64 + jj8] = w;
    } else {
      // g -> V[b][ch][m]: thread = (ch_l = tid>>2, m8 = (tid&3)*8)
      int ch_l = tid >> 2;
      int m8 = (tid & 3) * 8;
      f16x8 w;
#pragma unroll
      for (int i = 0; i < 8; i++) {
        int mm = m8 + i;
        f16x2 p0 = *(const f16x2*)&Pool[ch_l * 132 + 2 * mm];
        f16x2 p1 = *(const f16x2*)&Pool[ch_l * 132 + 64 + 2 * mm];
        float v = fmaxf(fmaxf((float)p0[0], (float)p0[1]),
                        fmaxf((float)p1[0], (float)p1[1]));
        w[i] = (f16)v;
      }
      int ch = (mt - 2) * 64 + ch_l;
      *(f16x8*)&V[(((size_t)b * 256 + ch) << 10) + nt * 32 + m8] = w;
    }
  }
}

// -------------------------------------------------------------------------
// Flash attention, swapped-QK^T (16x16): Q [4096][64], K [1024][64],
// V [256][1024] -> att [n][c]. 512 thr = 8 waves = 4 rg(32q) x 2 cg(128ch).
// s = MFMA(kf, qf): lane (hi,l15) holds q-row l15 (per h-half), keys
// mf*16+hi*4+r -> lane-local softmax; P packed f16x4 -> wave-private LDS.
__global__ __launch_bounds__(512, 2)
void k_flash(const f16* __restrict__ Q, const f16* __restrict__ Kp,
             const f16* __restrict__ V, f16* __restrict__ att) {
  __shared__ f16 Klds[2][64 * 64];    // [key][ch] swizzled, 8KB each
  __shared__ f16 Vlds[2][256 * 64];   // [ch][key] swizzled, 32KB each
  __shared__ f16 Plds[8][32 * 72];    // per-wave P [q][key], 144B rows
  int b = blockIdx.y, qt = blockIdx.x;
  int tid = threadIdx.x;
  int lane = tid & 63, wave = tid >> 6;   // 8 waves
  int rg = wave >> 1, cg2 = wave & 1;     // row-group 0..3, channel-group 0..1
  int l15 = lane & 15, hi = lane >> 4;
  const f16* Kb = Kp + ((size_t)b << 16);
  const f16* Vb = V + ((size_t)b << 18);
  f16* Pw = &Plds[wave][0];
  const float L2E = 1.44269504f;
  // Q fragments: rows qt*128 + rg*32 + h*16 + l15
  f16x8 qf[2][2];
#pragma unroll
  for (int h = 0; h < 2; h++)
#pragma unroll
    for (int ks = 0; ks < 2; ks++)
      qf[h][ks] = *(const f16x8*)(
          Q + (((size_t)b * 4096 + qt * 128 + rg * 32 + h * 16 + l15) << 6) +
          ks * 32 + hi * 8);
  f32x4 o[2][8];
#pragma unroll
  for (int h = 0; h < 2; h++)
#pragma unroll
    for (int i = 0; i < 8; i++) o[h][i] = (f32x4){0, 0, 0, 0};
  float mrow[2] = {-1e30f, -1e30f};
  float lrow[2] = {0.f, 0.f};

  int cbase = hi * 16;  // byte offset of this lane's 16B k-chunk within a 128B row

#define STAGE(bufi, kt)                                                          \
  {                                                                              \
    {                                                                            \
      int chunk = tid;                                                           \
      int row = chunk >> 3, cc = chunk & 7, scc = cc ^ (row & 7);                \
      gload16(Kb + (((kt) * 64 + row) << 6) + scc * 8,                           \
              (char*)&Klds[bufi][0] + chunk * 16);                               \
    }                                                                            \
    _Pragma("unroll") for (int i = 0; i < 4; i++) {                              \
      int chunk = i * 512 + tid;                                                 \
      int row = chunk >> 3, cc = chunk & 7, scc = cc ^ (row & 7);                \
      gload16(Vb + ((size_t)row << 10) + (kt) * 64 + scc * 8,                    \
              (char*)&Vlds[bufi][0] + chunk * 16);                               \
    }                                                                            \
  }

  STAGE(0, 0);
  __syncthreads();
  int buf = 0;
  for (int kt = 0; kt < 16; ++kt) {
    if (kt < 15) STAGE(buf ^ 1, kt + 1);
    // ---- S^T = K Q^T: lane holds q-row l15 (h-half), keys mf*16+hi*4+r
    f32x4 s[2][4];
#pragma unroll
    for (int h = 0; h < 2; h++)
#pragma unroll
      for (int mf = 0; mf < 4; mf++) s[h][mf] = (f32x4){0, 0, 0, 0};
#pragma unroll
    for (int ks = 0; ks < 2; ks++) {
      f16x8 kf[4];
#pragma unroll
      for (int mf = 0; mf < 4; mf++) {
        int row = mf * 16 + l15;
        kf[mf] = *(const f16x8*)((const char*)&Klds[buf][0] + row * 128 +
                                 ((cbase + ks * 64) ^ ((row & 7) << 4)));
      }
#pragma unroll
      for (int h = 0; h < 2; h++)
#pragma unroll
        for (int mf = 0; mf < 4; mf++)
          s[h][mf] = MFMA16(kf[mf], qf[h][ks], s[h][mf]);
    }
    // ---- lane-local online softmax (defer-max THR=8)
    float pmax[2];
#pragma unroll
    for (int h = 0; h < 2; h++) {
      float t0 = fmaxf(fmaxf(s[h][0][0], s[h][1][0]), fmaxf(s[h][2][0], s[h][3][0]));
      float t1 = fmaxf(fmaxf(s[h][0][1], s[h][1][1]), fmaxf(s[h][2][1], s[h][3][1]));
      float t2 = fmaxf(fmaxf(s[h][0][2], s[h][1][2]), fmaxf(s[h][2][2], s[h][3][2]));
      float t3 = fmaxf(fmaxf(s[h][0][3], s[h][1][3]), fmaxf(s[h][2][3], s[h][3][3]));
      float mx = fmaxf(fmaxf(t0, t1), fmaxf(t2, t3));
      mx = fmaxf(mx, __shfl_xor(mx, 16, 64));
      mx = fmaxf(mx, __shfl_xor(mx, 32, 64));
      pmax[h] = mx;
    }
    bool need = (pmax[0] > mrow[0] + 8.f) || (pmax[1] > mrow[1] + 8.f);
    if (__any(need)) {
#pragma unroll
      for (int h = 0; h < 2; h++) {
        float mnew = fmaxf(mrow[h], pmax[h]);
        float corr = __builtin_amdgcn_exp2f((mrow[h] - mnew) * L2E);
        lrow[h] *= corr;
        mrow[h] = mnew;
#pragma unroll
        for (int r = 0; r < 4; r++) {
          float cr = __shfl(corr, (hi << 4) + (hi << 2) + r, 64);
#pragma unroll
          for (int cf = 0; cf < 8; cf++) o[h][cf][r] *= cr;
        }
      }
    }
#pragma unroll
    for (int h = 0; h < 2; h++) {
      float e[4][4];
#pragma unroll
      for (int mf = 0; mf < 4; mf++)
#pragma unroll
        for (int r = 0; r < 4; r++)
          e[mf][r] = __builtin_amdgcn_exp2f((s[h][mf][r] - mrow[h]) * L2E);
      // pack & store P row (key k = mf*16 + hi*4 + r at byte k*2)
#pragma unroll
      for (int mf = 0; mf < 4; mf++) {
        f16x4 w = {(f16)e[mf][0], (f16)e[mf][1], (f16)e[mf][2], (f16)e[mf][3]};
        *(f16x4*)((char*)Pw + (h * 16 + l15) * 144 + mf * 32 + hi * 8) = w;
      }
      float u0 = (e[0][0] + e[1][0]) + (e[2][0] + e[3][0]);
      float u1 = (e[0][1] + e[1][1]) + (e[2][1] + e[3][1]);
      float u2 = (e[0][2] + e[1][2]) + (e[2][2] + e[3][2]);
      float u3 = (e[0][3] + e[1][3]) + (e[2][3] + e[3][3]);
      float sum = (u0 + u1) + (u2 + u3);
      sum += __shfl_xor(sum, 16, 64);
      sum += __shfl_xor(sum, 32, 64);
      lrow[h] += sum;
    }
    // ---- PV: this wave covers channels cg2*128 .. cg2*128+127
#pragma unroll
    for (int ks = 0; ks < 2; ks++) {
      f16x8 af[2];
#pragma unroll
      for (int h = 0; h < 2; h++)
        af[h] = *(const f16x8*)((char*)Pw + (h * 16 + l15) * 144 + ks * 64 + hi * 16);
      __builtin_amdgcn_s_setprio(1);
#pragma unroll
      for (int cg = 0; cg < 2; cg++) {
        f16x8 vf[4];
#pragma unroll
        for (int u = 0; u < 4; u++) {
          int row = (cg2 * 8 + cg * 4 + u) * 16 + l15;
          vf[u] = *(const f16x8*)((const char*)&Vlds[buf][0] + row * 128 +
                                  ((cbase + ks * 64) ^ ((row & 7) << 4)));
        }
#pragma unroll
        for (int h = 0; h < 2; h++)
#pragma unroll
          for (int u = 0; u < 4; u++)
            o[h][cg * 4 + u] = MFMA16(af[h], vf[u], o[h][cg * 4 + u]);
      }
      __builtin_amdgcn_s_setprio(0);
    }
    __syncthreads();
    buf ^= 1;
  }
#undef STAGE
  int nbase = qt * 128 + rg * 32 + hi * 4;
#pragma unroll
  for (int h = 0; h < 2; h++) {
    float inv = 1.f / lrow[h];
#pragma unroll
    for (int r = 0; r < 4; r++) {
      float iv = __shfl(inv, (hi << 4) + (hi << 2) + r, 64);
#pragma unroll
      for (int cf = 0; cf < 8; cf++) {
        int n = nbase + h * 16 + r;
        int c = cg2 * 128 + cf * 16 + l15;
        att[(((size_t)b * 4096 + n) << 8) + c] = (f16)(o[h][cf][r] * iv);
      }
    }
  }
}

// -------------------------------------------------------------------------
// Output GEMM: out[b][o][n] = sum_{k<512} Wcat[o][k] * Bcat[n][k], Bcat=[att|xT].
__global__ __launch_bounds__(256, 2)
void k_gemm_out(const f16* __restrict__ Wcat, const f16* __restrict__ att,
                const f16* __restrict__ xT, float* __restrict__ out) {
  __shared__ f16 Alds[128 * 64];
  __shared__ f16 Blds[128 * 64];
  int b = blockIdx.z, mt = blockIdx.y, nt = blockIdx.x;
  int lane = threadIdx.x & 63, wave = threadIdx.x >> 6;
  int wm = wave >> 1, wn = wave & 1;
  f32x4 acc[4][4];
#pragma unroll
  for (int mf = 0; mf < 4; mf++)
#pragma unroll
    for (int nf = 0; nf < 4; nf++) acc[mf][nf] = (f32x4){0, 0, 0, 0};
  const f16* Abase = Wcat + (size_t)(mt * 128) * 512;
  for (int k0 = 0; k0 < 512; k0 += 64) {
    __syncthreads();
#pragma unroll
    for (int i = 0; i < 4; i++) {
      int chunk = i * 256 + threadIdx.x;
      int row = chunk >> 3, cc = chunk & 7, scc = cc ^ (row & 7);
      gload16(Abase + row * 512 + k0 + scc * 8, (char*)Alds + (i * 256 + wave * 64) * 16);
    }
    const f16* Bcol = (k0 < 256) ? (att + (((size_t)b * 4096 + nt * 128) << 8))
                                 : (xT + (((size_t)b * 4096 + nt * 128) << 8));
    int kk = (k0 < 256) ? k0 : (k0 - 256);
#pragma unroll
    for (int i = 0; i < 4; i++) {
      int chunk = i * 256 + threadIdx.x;
      int row = chunk >> 3, cc = chunk & 7, scc = cc ^ (row & 7);
      gload16(Bcol + (row << 8) + kk + scc * 8, (char*)Blds + (i * 256 + wave * 64) * 16);
    }
    __syncthreads();
#pragma unroll
    for (int ks = 0; ks < 2; ks++) {
      int cb = ((lane >> 4) * 8 + ks * 32) * 2;
      f16x8 af[4], bf[4];
#pragma unroll
      for (int mf = 0; mf < 4; mf++) {
        int row = wm * 64 + mf * 16 + (lane & 15);
        af[mf] = *(const f16x8*)((const char*)Alds + row * 128 + (cb ^ ((row & 7) << 4)));
      }
#pragma unroll
      for (int nf = 0; nf < 4; nf++) {
        int row = wn * 64 + nf * 16 + (lane & 15);
        bf[nf] = *(const f16x8*)((const char*)Blds + row * 128 + (cb ^ ((row & 7) << 4)));
      }
#pragma unroll
      for (int mf = 0; mf < 4; mf++)
#pragma unroll
        for (int nf = 0; nf < 4; nf++) acc[mf][nf] = MFMA16(af[mf], bf[nf], acc[mf][nf]);
    }
  }
#pragma unroll
  for (int mf = 0; mf < 4; mf++)
#pragma unroll
    for (int nf = 0; nf < 4; nf++)
#pragma unroll
      for (int r = 0; r < 4; r++) {
        int oo = mt * 128 + wm * 64 + mf * 16 + (lane >> 4) * 4 + r;
        int n = nt * 128 + wn * 64 + nf * 16 + (lane & 15);
        out[(((size_t)b * 512 + oo) << 12) + n] = acc[mf][nf][r];
      }
}

// -------------------------------------------------------------------------
extern "C" void kernel_launch(void* const* d_in, const int* in_sizes, int n_in,
                              void* d_out, int out_size, void* d_ws, size_t ws_size,
                              hipStream_t stream) {
  const float* x = (const float*)d_in[0];
  const float* wt = (const float*)d_in[1];
  const float* wp = (const float*)d_in[2];
  const float* wg = (const float*)d_in[3];
  const float* wo = (const float*)d_in[4];
  const float* wr = (const float*)d_in[5];
  const float* gm = (const float*)d_in[6];
  float* out = (float*)d_out;
  char* ws = (char*)d_ws;
  const size_t MB = 1024 * 1024;
  f16* xT = (f16*)(ws);
  f16* Qb = (f16*)(ws + 16 * MB);
  f16* Kp = (f16*)(ws + 20 * MB);
  f16* Vb = (f16*)(ws + 21 * MB);
  f16* Wproj = (f16*)(ws + 25 * MB);
  f16* Wcat = (f16*)(ws + 25 * MB + 512 * 1024);
  f16* att = (f16*)(ws + 26 * MB);

  hipLaunchKernelGGL(k_prep_w, dim3(1408), dim3(256), 0, stream, wt, wp, wg, wo, wr, gm,
                     Wproj, Wcat);
  hipLaunchKernelGGL(k_transpose, dim3(4, 64, 8), dim3(256), 0, stream, x, xT);
  hipLaunchKernelGGL(k_gemm_projq, dim3(32, 6, 8), dim3(256), 0, stream, xT, Wproj, Qb,
                     Kp, Vb);
  hipLaunchKernelGGL(k_flash, dim3(32, 8), dim3(512), 0, stream, Qb, Kp, Vb, att);
  hipLaunchKernelGGL(k_gemm_out, dim3(32, 4, 8), dim3(256), 0, stream, Wcat, att, xT, out);
}